// Round 1
// baseline (224.771 us; speedup 1.0000x reference)
//
#include <hip/hip_runtime.h>

#define TQ 512
#define TK 256
#define BB 8
#define CC 128

__device__ __forceinline__ float fexp2(float x) { return __builtin_amdgcn_exp2f(x); }
__device__ __forceinline__ float frcp(float x)  { return __builtin_amdgcn_rcpf(x); }

// 2*log2(e): projections pre-scaled so exp2(qs+ks) == e^(2(q+k))
#define SCALE2L2E 2.8853900817779268f
#define L2E 1.4426950408889634f

// ---------------- Kernel 1: projection GEMM ----------------
// Y(rows x 128) = X(rows x K) @ W(128 x K)^T
// X row r corresponds to (t = r/8, b = r%8) from (T, B, K) input.
// LAYOUT 0: Y[b][t][c]   LAYOUT 1: Y[b][c][t]
template<int K, int LAYOUT>
__global__ __launch_bounds__(256) void proj_kernel(const float* __restrict__ X,
                                                   const float* __restrict__ W,
                                                   float* __restrict__ Y,
                                                   int Tdim, float scale) {
    __shared__ float xs[16][36];   // [kk][row], padded: stage writes 2-way, reads broadcast
    __shared__ float ws[16][132];  // [kk][col], padded

    const int tid = threadIdx.x;
    const int r0B = blockIdx.x * 32;
    const int rg = tid >> 5;          // 0..7  -> rows rg*4..rg*4+3
    const int c4 = (tid & 31) << 2;   // 0,4,...,124

    float acc[4][4];
#pragma unroll
    for (int i = 0; i < 4; ++i)
#pragma unroll
        for (int j = 0; j < 4; ++j) acc[i][j] = 0.f;

    for (int k0 = 0; k0 < K; k0 += 16) {
        __syncthreads();
        for (int i = tid; i < 32 * 16; i += 256) {
            int r = i >> 4, kk = i & 15;
            xs[kk][r] = X[(r0B + r) * K + k0 + kk];
        }
        for (int i = tid; i < 128 * 16; i += 256) {
            int c = i >> 4, kk = i & 15;
            ws[kk][c] = W[c * K + k0 + kk];
        }
        __syncthreads();
#pragma unroll
        for (int kk = 0; kk < 16; ++kk) {
            const float4 xv = *(const float4*)&xs[kk][rg << 2];
            const float4 wv = *(const float4*)&ws[kk][c4];
            const float xa[4] = {xv.x, xv.y, xv.z, xv.w};
            const float wa[4] = {wv.x, wv.y, wv.z, wv.w};
#pragma unroll
            for (int i = 0; i < 4; ++i)
#pragma unroll
                for (int j = 0; j < 4; ++j)
                    acc[i][j] = fmaf(xa[i], wa[j], acc[i][j]);
        }
    }

#pragma unroll
    for (int i = 0; i < 4; ++i) {
        int grow = r0B + (rg << 2) + i;
        int t = grow >> 3, b = grow & 7;
#pragma unroll
        for (int j = 0; j < 4; ++j) {
            float v = acc[i][j] * scale;
            int c = c4 + j;
            if (LAYOUT == 0) Y[(b * Tdim + t) * CC + c] = v;
            else             Y[(b * CC + c) * Tdim + t] = v;
        }
    }
}

// ---------------- Kernel 2: scores + softmax ----------------
// Block: 4 waves x 2 q-rows = 8 q-rows. Lane = k within 64-wide k-tile.
// kl[c][64] in LDS (conflict-free); q-row + Wvec via scalar loads (uniform ptrs).
__global__ __launch_bounds__(256) void attn_kernel(const float* __restrict__ qp,
                                                   const float* __restrict__ kp,
                                                   const float* __restrict__ Wvec,
                                                   float* __restrict__ attn_out,
                                                   float* __restrict__ pT) {
    __shared__ float kl[128 * 64];
    __shared__ float pl[8][264];

    const int tid = threadIdx.x;
    const int lane = tid & 63;
    const int w = __builtin_amdgcn_readfirstlane(tid >> 6);
    const int b = blockIdx.y;
    const int q0B = blockIdx.x * 8;
    const int q0 = q0B + w * 2;

    const float* __restrict__ qr0 = qp + (b * TQ + q0) * CC;
    const float* __restrict__ qr1 = qr0 + CC;

    // sum of Wvec (unscaled), all lanes
    float sw = Wvec[lane] + Wvec[64 + lane];
#pragma unroll
    for (int m = 32; m >= 1; m >>= 1) sw += __shfl_xor(sw, m, 64);

    float sc0[4], sc1[4];
    for (int tile = 0; tile < 4; ++tile) {
        const int k0 = tile * 64;
        for (int i = tid; i < 128 * 16; i += 256) {
            int c = i >> 4, j4 = (i & 15) << 2;
            float4 v = *(const float4*)&kp[(b * CC + c) * TK + k0 + j4];
            *(float4*)&kl[c * 64 + j4] = v;
        }
        __syncthreads();

        float a0 = 0.f, a1 = 0.f;
        for (int cc = 0; cc < 128; cc += 32) {
#pragma unroll
            for (int u = 0; u < 32; ++u) {
                const int c = cc + u;
                const float kv = kl[c * 64 + lane];
                const float wc = Wvec[c];        // s_load (uniform)
                const float qa = qr0[c];         // s_load (uniform)
                const float qb = qr1[c];         // s_load (uniform)
                float t0 = fexp2(qa + kv);
                a0 = fmaf(wc, frcp(t0 + 1.f), a0);
                float t1 = fexp2(qb + kv);
                a1 = fmaf(wc, frcp(t1 + 1.f), a1);
            }
        }
        sc0[tile] = sw - 2.f * a0;
        sc1[tile] = sw - 2.f * a1;
        __syncthreads();
    }

    // softmax over 256 (4 regs x 64 lanes) per row
    float m0 = fmaxf(fmaxf(sc0[0], sc0[1]), fmaxf(sc0[2], sc0[3]));
    float m1 = fmaxf(fmaxf(sc1[0], sc1[1]), fmaxf(sc1[2], sc1[3]));
#pragma unroll
    for (int m = 32; m >= 1; m >>= 1) {
        m0 = fmaxf(m0, __shfl_xor(m0, m, 64));
        m1 = fmaxf(m1, __shfl_xor(m1, m, 64));
    }
    float e0[4], e1[4], s0 = 0.f, s1 = 0.f;
#pragma unroll
    for (int t = 0; t < 4; ++t) {
        e0[t] = fexp2((sc0[t] - m0) * L2E); s0 += e0[t];
        e1[t] = fexp2((sc1[t] - m1) * L2E); s1 += e1[t];
    }
#pragma unroll
    for (int m = 32; m >= 1; m >>= 1) {
        s0 += __shfl_xor(s0, m, 64);
        s1 += __shfl_xor(s1, m, 64);
    }
    const float r0 = frcp(s0), r1 = frcp(s1);

#pragma unroll
    for (int t = 0; t < 4; ++t) {
        float p0 = e0[t] * r0, p1 = e1[t] * r1;
        attn_out[(b * TQ + q0)     * TK + t * 64 + lane] = p0;
        attn_out[(b * TQ + q0 + 1) * TK + t * 64 + lane] = p1;
        pl[w * 2 + 0][t * 64 + lane] = p0;
        pl[w * 2 + 1][t * 64 + lane] = p1;
    }
    __syncthreads();

    // cooperative transpose dump: pT[b][k][q0B + j]
    for (int i = tid; i < 2048; i += 256) {
        int k = i >> 3, j = i & 7;
        pT[(b * TK + k) * TQ + q0B + j] = pl[j][k];
    }
}

// ---------------- Kernel 3: PV ----------------
// out[b][c][q] = sum_k p[b][q][k] * v[b][k][c]
// thread = q; v rows via block-uniform scalar loads; p via coalesced pT.
__global__ __launch_bounds__(256) void pv_kernel(const float* __restrict__ pT,
                                                 const float* __restrict__ vp,
                                                 float* __restrict__ out) {
    const int tid = threadIdx.x;
    const int qh = blockIdx.x;   // 0..1
    const int cg = blockIdx.y;   // 0..15 (8 c's each)
    const int b  = blockIdx.z;   // 0..7
    const int q = qh * 256 + tid;

    const float* __restrict__ vb = vp + (b * TK) * CC + cg * 8;
    const float* __restrict__ pb = pT + (b * TK) * TQ + q;

    float acc[8];
#pragma unroll
    for (int j = 0; j < 8; ++j) acc[j] = 0.f;

#pragma unroll 4
    for (int k = 0; k < TK; ++k) {
        const float p = pb[k * TQ];
        const float* __restrict__ vr = vb + k * CC;  // uniform -> s_load
#pragma unroll
        for (int j = 0; j < 8; ++j) acc[j] = fmaf(p, vr[j], acc[j]);
    }

#pragma unroll
    for (int j = 0; j < 8; ++j)
        out[(b * CC + cg * 8 + j) * TQ + q] = acc[j];
}

extern "C" void kernel_launch(void* const* d_in, const int* in_sizes, int n_in,
                              void* d_out, int out_size, void* d_ws, size_t ws_size,
                              hipStream_t stream) {
    const float* queries = (const float*)d_in[0];
    const float* keys    = (const float*)d_in[1];
    const float* values  = (const float*)d_in[2];
    const float* Wq      = (const float*)d_in[3];
    const float* Wk      = (const float*)d_in[4];
    const float* Wv      = (const float*)d_in[5];
    const float* Wvec    = (const float*)d_in[6];

    float* out  = (float*)d_out;                 // (8,128,512)
    float* attn = out + BB * CC * TQ;            // (8,512,256)

    float* ws = (float*)d_ws;
    float* qp = ws;                    // 4096*128 (scaled by 2*log2e)
    float* kp = qp + 4096 * CC;        // [b][c][t], 2048*128, scaled
    float* vp = kp + 2048 * CC;        // [b][t][c], 2048*128
    float* pT = vp + 2048 * CC;        // [b][k][q], 8*256*512

    proj_kernel<80, 0><<<dim3(128), 256, 0, stream>>>(queries, Wq, qp, TQ, SCALE2L2E);
    proj_kernel<640, 1><<<dim3(64), 256, 0, stream>>>(keys, Wk, kp, TK, SCALE2L2E);
    proj_kernel<640, 0><<<dim3(64), 256, 0, stream>>>(values, Wv, vp, TK, 1.0f);
    attn_kernel<<<dim3(64, 8), 256, 0, stream>>>(qp, kp, Wvec, attn, pT);
    pv_kernel<<<dim3(2, 16, 8), 256, 0, stream>>>(pT, vp, out);
}

// Round 2
// 118.311 us; speedup vs baseline: 1.8998x; 1.8998x over previous
//
#include <hip/hip_runtime.h>

#define TQ 512
#define TK 256
#define BB 8
#define CC 128

// 2*log2(e): projections pre-scaled so exp2(qs+ks) == e^(2(q+k))
#define SCALE2L2E 2.8853900817779268f
#define L2E 1.4426950408889634f

__device__ __forceinline__ float fexp2(float x) { return __builtin_amdgcn_exp2f(x); }
__device__ __forceinline__ float frcp(float x)  { return __builtin_amdgcn_rcpf(x); }

// ---------------- Kernel 1: projection GEMM ----------------
// Y(rows x 128) = X(rows x K) @ W(128 x K)^T ; row r -> (t = r/8, b = r%8).
// Block: 16 rows x 64 cols (c-half), 128 threads, thread = 4r x 2c.
// grid.y = tensor*2 + chalf (NY tensors fused per launch).
// LDS: X slab staged once; W in double-buffered 32-k transposed chunks.
template<int K, int KC, int NY>
__global__ __launch_bounds__(128) void proj_kernel(
    const float* __restrict__ X0, const float* __restrict__ W0, float* __restrict__ Y0,
    float sc0, int lay0,
    const float* __restrict__ X1, const float* __restrict__ W1, float* __restrict__ Y1,
    float sc1, int lay1,
    int Tdim)
{
    constexpr int NCH = K / KC;
    constexpr int NB = (NCH > 1) ? 2 : 1;
    __shared__ float xs[16][K];
    __shared__ float ws[NB][KC][68];

    const int tens = (NY == 2) ? (int)(blockIdx.y >> 1) : 0;
    const int ch = blockIdx.y & 1;
    const float* __restrict__ X = X0; const float* __restrict__ W = W0;
    float* __restrict__ Y = Y0; float scale = sc0; int lay = lay0;
    if (NY == 2 && tens == 1) { X = X1; W = W1; Y = Y1; scale = sc1; lay = lay1; }

    const int tid = threadIdx.x;
    const int r0B = blockIdx.x * 16;
    const int c0 = ch * 64;

    // stage X slab once (16 rows x K), rows are contiguous (t*8+b ordering)
    for (int i = tid; i < 16 * (K / 4); i += 128) {
        int r = i / (K / 4), j = i % (K / 4);
        *(float4*)&xs[r][j * 4] = *(const float4*)&X[(r0B + r) * K + j * 4];
    }

    auto stageW = [&](int kc, int buf) {
        for (int i = tid; i < 64 * (KC / 4); i += 128) {
            int c = i / (KC / 4), j = i % (KC / 4);
            float4 w = *(const float4*)&W[(c0 + c) * K + kc * KC + j * 4];
            ws[buf][j * 4 + 0][c] = w.x;
            ws[buf][j * 4 + 1][c] = w.y;
            ws[buf][j * 4 + 2][c] = w.z;
            ws[buf][j * 4 + 3][c] = w.w;
        }
    };

    stageW(0, 0);
    __syncthreads();

    const int rq = tid >> 5;          // 0..3 -> rows rq*4 .. rq*4+3
    const int c2 = (tid & 31) * 2;    // 0,2,...,62

    float acc[4][2];
#pragma unroll
    for (int i = 0; i < 4; ++i) { acc[i][0] = 0.f; acc[i][1] = 0.f; }

    for (int kc = 0; kc < NCH; ++kc) {
        if (NB == 2 && kc + 1 < NCH) stageW(kc + 1, (kc + 1) & 1);
        const int buf = (NB == 2) ? (kc & 1) : 0;
#pragma unroll
        for (int k4 = 0; k4 < KC / 4; ++k4) {
            float2 wv[4];
            float4 xv[4];
#pragma unroll
            for (int m = 0; m < 4; ++m)
                wv[m] = *(const float2*)&ws[buf][k4 * 4 + m][c2];
#pragma unroll
            for (int i = 0; i < 4; ++i)
                xv[i] = *(const float4*)&xs[rq * 4 + i][kc * KC + k4 * 4];
#pragma unroll
            for (int i = 0; i < 4; ++i) {
                acc[i][0] = fmaf(xv[i].x, wv[0].x, acc[i][0]);
                acc[i][1] = fmaf(xv[i].x, wv[0].y, acc[i][1]);
                acc[i][0] = fmaf(xv[i].y, wv[1].x, acc[i][0]);
                acc[i][1] = fmaf(xv[i].y, wv[1].y, acc[i][1]);
                acc[i][0] = fmaf(xv[i].z, wv[2].x, acc[i][0]);
                acc[i][1] = fmaf(xv[i].z, wv[2].y, acc[i][1]);
                acc[i][0] = fmaf(xv[i].w, wv[3].x, acc[i][0]);
                acc[i][1] = fmaf(xv[i].w, wv[3].y, acc[i][1]);
            }
        }
        __syncthreads();
    }

#pragma unroll
    for (int i = 0; i < 4; ++i) {
        int grow = r0B + rq * 4 + i;
        int t = grow >> 3, b = grow & 7;
        float v0 = acc[i][0] * scale, v1 = acc[i][1] * scale;
        int c = c0 + c2;
        if (lay == 0) {
            *(float2*)&Y[(b * Tdim + t) * CC + c] = make_float2(v0, v1);
        } else {
            Y[(b * CC + c) * Tdim + t] = v0;
            Y[(b * CC + c + 1) * Tdim + t] = v1;
        }
    }
}

// ---------------- Kernel 2: scores + softmax ----------------
// Block: 4 waves x 2 q-rows = 8 q-rows. Lane = k within 64-wide k-tile.
// kl[c][64] in LDS (conflict-free); q-row + Wvec via scalar loads (uniform ptrs).
__global__ __launch_bounds__(256) void attn_kernel(const float* __restrict__ qp,
                                                   const float* __restrict__ kp,
                                                   const float* __restrict__ Wvec,
                                                   float* __restrict__ attn_out,
                                                   float* __restrict__ pT) {
    __shared__ float kl[128 * 64];
    __shared__ float pl[8][264];

    const int tid = threadIdx.x;
    const int lane = tid & 63;
    const int w = __builtin_amdgcn_readfirstlane(tid >> 6);
    const int b = blockIdx.y;
    const int q0B = blockIdx.x * 8;
    const int q0 = q0B + w * 2;

    const float* __restrict__ qr0 = qp + (b * TQ + q0) * CC;
    const float* __restrict__ qr1 = qr0 + CC;

    // sum of Wvec (unscaled), all lanes
    float sw = Wvec[lane] + Wvec[64 + lane];
#pragma unroll
    for (int m = 32; m >= 1; m >>= 1) sw += __shfl_xor(sw, m, 64);

    float sc0[4], sc1[4];
    for (int tile = 0; tile < 4; ++tile) {
        const int k0 = tile * 64;
        for (int i = tid; i < 128 * 16; i += 256) {
            int c = i >> 4, j4 = (i & 15) << 2;
            float4 v = *(const float4*)&kp[(b * CC + c) * TK + k0 + j4];
            *(float4*)&kl[c * 64 + j4] = v;
        }
        __syncthreads();

        float a0 = 0.f, a1 = 0.f;
        for (int cc = 0; cc < 128; cc += 32) {
#pragma unroll
            for (int u = 0; u < 32; ++u) {
                const int c = cc + u;
                const float kv = kl[c * 64 + lane];
                const float wc = Wvec[c];        // s_load (uniform)
                const float qa = qr0[c];         // s_load (uniform)
                const float qb = qr1[c];         // s_load (uniform)
                float t0 = fexp2(qa + kv);
                a0 = fmaf(wc, frcp(t0 + 1.f), a0);
                float t1 = fexp2(qb + kv);
                a1 = fmaf(wc, frcp(t1 + 1.f), a1);
            }
        }
        sc0[tile] = sw - 2.f * a0;
        sc1[tile] = sw - 2.f * a1;
        __syncthreads();
    }

    // softmax over 256 (4 regs x 64 lanes) per row
    float m0 = fmaxf(fmaxf(sc0[0], sc0[1]), fmaxf(sc0[2], sc0[3]));
    float m1 = fmaxf(fmaxf(sc1[0], sc1[1]), fmaxf(sc1[2], sc1[3]));
#pragma unroll
    for (int m = 32; m >= 1; m >>= 1) {
        m0 = fmaxf(m0, __shfl_xor(m0, m, 64));
        m1 = fmaxf(m1, __shfl_xor(m1, m, 64));
    }
    float e0[4], e1[4], s0 = 0.f, s1 = 0.f;
#pragma unroll
    for (int t = 0; t < 4; ++t) {
        e0[t] = fexp2((sc0[t] - m0) * L2E); s0 += e0[t];
        e1[t] = fexp2((sc1[t] - m1) * L2E); s1 += e1[t];
    }
#pragma unroll
    for (int m = 32; m >= 1; m >>= 1) {
        s0 += __shfl_xor(s0, m, 64);
        s1 += __shfl_xor(s1, m, 64);
    }
    const float r0 = frcp(s0), r1 = frcp(s1);

#pragma unroll
    for (int t = 0; t < 4; ++t) {
        float p0 = e0[t] * r0, p1 = e1[t] * r1;
        attn_out[(b * TQ + q0)     * TK + t * 64 + lane] = p0;
        attn_out[(b * TQ + q0 + 1) * TK + t * 64 + lane] = p1;
        pl[w * 2 + 0][t * 64 + lane] = p0;
        pl[w * 2 + 1][t * 64 + lane] = p1;
    }
    __syncthreads();

    // cooperative transpose dump: pT[b][k][q0B + j]
    for (int i = tid; i < 2048; i += 256) {
        int k = i >> 3, j = i & 7;
        pT[(b * TK + k) * TQ + q0B + j] = pl[j][k];
    }
}

// ---------------- Kernel 3: PV ----------------
// out[b][c][q] = sum_k p[b][q][k] * v[b][k][c]
// grid (4 q-quarters, 8 c-groups, 8 b) x 256 thr; ch = wave-pair selects 8-c sub-block.
// v rows via wave-uniform s_loads; p via coalesced pT.
__global__ __launch_bounds__(256) void pv_kernel(const float* __restrict__ pT,
                                                 const float* __restrict__ vp,
                                                 float* __restrict__ out) {
    const int tid = threadIdx.x;
    const int qh = blockIdx.x;   // 0..3
    const int cg = blockIdx.y;   // 0..7
    const int b  = blockIdx.z;   // 0..7
    const int ch = __builtin_amdgcn_readfirstlane(tid >> 7);
    const int q = qh * 128 + (tid & 127);
    const int c0 = cg * 16 + ch * 8;

    const float* __restrict__ vb = vp + b * TK * CC + c0;
    const float* __restrict__ pb = pT + b * TK * TQ + q;

    float acc[8];
#pragma unroll
    for (int j = 0; j < 8; ++j) acc[j] = 0.f;

#pragma unroll 8
    for (int k = 0; k < TK; ++k) {
        const float p = pb[k * TQ];
        const float* __restrict__ vr = vb + k * CC;  // uniform -> s_load
#pragma unroll
        for (int j = 0; j < 8; ++j) acc[j] = fmaf(p, vr[j], acc[j]);
    }

#pragma unroll
    for (int j = 0; j < 8; ++j)
        out[(b * CC + c0 + j) * TQ + q] = acc[j];
}

extern "C" void kernel_launch(void* const* d_in, const int* in_sizes, int n_in,
                              void* d_out, int out_size, void* d_ws, size_t ws_size,
                              hipStream_t stream) {
    const float* queries = (const float*)d_in[0];
    const float* keys    = (const float*)d_in[1];
    const float* values  = (const float*)d_in[2];
    const float* Wq      = (const float*)d_in[3];
    const float* Wk      = (const float*)d_in[4];
    const float* Wv      = (const float*)d_in[5];
    const float* Wvec    = (const float*)d_in[6];

    float* out  = (float*)d_out;                 // (8,128,512)
    float* attn = out + BB * CC * TQ;            // (8,512,256)

    float* ws = (float*)d_ws;
    float* qp = ws;                    // [b][t][c] 4096*128, scaled by 2*log2e
    float* kp = qp + 4096 * CC;        // [b][c][t] 2048*128, scaled
    float* vp = kp + 2048 * CC;        // [b][t][c] 2048*128
    float* pT = vp + 2048 * CC;        // [b][k][q] 8*256*512

    // keys + values fused: 128 row-tiles x (2 tensors x 2 c-halves)
    proj_kernel<640, 32, 2><<<dim3(128, 4), 128, 0, stream>>>(
        keys, Wk, kp, SCALE2L2E, 1,
        values, Wv, vp, 1.0f, 0, TK);
    // queries: 256 row-tiles x 2 c-halves
    proj_kernel<80, 80, 1><<<dim3(256, 2), 128, 0, stream>>>(
        queries, Wq, qp, SCALE2L2E, 0,
        nullptr, nullptr, nullptr, 0.f, 0, TQ);
    attn_kernel<<<dim3(64, 8), 256, 0, stream>>>(qp, kp, Wvec, attn, pT);
    pv_kernel<<<dim3(4, 8, 8), 256, 0, stream>>>(pT, vp, out);
}

// Round 3
// 104.736 us; speedup vs baseline: 2.1461x; 1.1296x over previous
//
#include <hip/hip_runtime.h>

#define TQ 512
#define TK 256
#define BB 8
#define CC 128

// 2*log2(e): projections pre-scaled so exp2(qs+ks) == e^(2(q+k))
#define SCALE2L2E 2.8853900817779268f
#define L2E 1.4426950408889634f

__device__ __forceinline__ float fexp2(float x) { return __builtin_amdgcn_exp2f(x); }
__device__ __forceinline__ float frcp(float x)  { return __builtin_amdgcn_rcpf(x); }

// ---------------- Kernel 1: fused projection GEMMs ----------------
// Y(rows x 128) = X(rows x K) @ W(128 x K)^T ; row r -> (t = r/8, b = r%8).
// Block tile: 32 rows x 64 cols (c-half), 256 threads.
// Thread: 4 rows x 2 adjacent cols. acc[4][2].
// LDS: W^T chunk ws[KC][68] (b64 reads, 2-way alias=free) + X chunk xs[32][KC+4]
// (b128 half-wave-broadcast reads). 16.5 KB -> 8 blocks/CU.
template<int K, int KC>
__device__ __forceinline__ void proj_tile(
    const float* __restrict__ X, const float* __restrict__ W,
    float* __restrict__ Y, float scale, int lay, int Tdim,
    int rowTile, int chalf, float* lds)
{
    constexpr int WROW = 68;
    constexpr int XPAD = KC + 4;
    constexpr int NCH = K / KC;
    float* ws = lds;                // [KC][WROW]
    float* xs = lds + KC * WROW;    // [32][XPAD]

    const int tid = threadIdx.x;
    const int r0 = rowTile * 32;
    const int c0 = chalf * 64;
    const int w = tid >> 6;
    const int l = tid & 63;
    const int rbase = w * 8 + (l >> 5) * 4;   // row offset within tile
    const int c2 = (l & 31) * 2;              // col pair within half

    float acc[4][2];
#pragma unroll
    for (int i = 0; i < 4; ++i) { acc[i][0] = 0.f; acc[i][1] = 0.f; }

    for (int kc = 0; kc < NCH; ++kc) {
        if (kc) __syncthreads();
        // stage X chunk: 32 rows x KC (rows contiguous in (T,B) flattening)
        for (int i = tid; i < 32 * (KC / 4); i += 256) {
            int r = i / (KC / 4), j4 = (i % (KC / 4)) * 4;
            *(float4*)&xs[r * XPAD + j4] =
                *(const float4*)&X[(r0 + r) * K + kc * KC + j4];
        }
        // stage W^T chunk: 64 cols x KC, transposed to ws[k][c]
        for (int i = tid; i < 64 * (KC / 4); i += 256) {
            int c = i / (KC / 4), j4 = (i % (KC / 4)) * 4;
            float4 wv4 = *(const float4*)&W[(c0 + c) * K + kc * KC + j4];
            ws[(j4 + 0) * WROW + c] = wv4.x;
            ws[(j4 + 1) * WROW + c] = wv4.y;
            ws[(j4 + 2) * WROW + c] = wv4.z;
            ws[(j4 + 3) * WROW + c] = wv4.w;
        }
        __syncthreads();
#pragma unroll
        for (int k4 = 0; k4 < KC / 4; ++k4) {
            float2 wv[4];
            float4 xv[4];
#pragma unroll
            for (int m = 0; m < 4; ++m)
                wv[m] = *(const float2*)&ws[(k4 * 4 + m) * WROW + c2];
#pragma unroll
            for (int i = 0; i < 4; ++i)
                xv[i] = *(const float4*)&xs[(rbase + i) * XPAD + k4 * 4];
#pragma unroll
            for (int i = 0; i < 4; ++i) {
                acc[i][0] = fmaf(xv[i].x, wv[0].x, acc[i][0]);
                acc[i][1] = fmaf(xv[i].x, wv[0].y, acc[i][1]);
                acc[i][0] = fmaf(xv[i].y, wv[1].x, acc[i][0]);
                acc[i][1] = fmaf(xv[i].y, wv[1].y, acc[i][1]);
                acc[i][0] = fmaf(xv[i].z, wv[2].x, acc[i][0]);
                acc[i][1] = fmaf(xv[i].z, wv[2].y, acc[i][1]);
                acc[i][0] = fmaf(xv[i].w, wv[3].x, acc[i][0]);
                acc[i][1] = fmaf(xv[i].w, wv[3].y, acc[i][1]);
            }
        }
    }

#pragma unroll
    for (int i = 0; i < 4; ++i) {
        int grow = r0 + rbase + i;
        int t = grow >> 3, b = grow & 7;
        float v0 = acc[i][0] * scale, v1 = acc[i][1] * scale;
        int c = c0 + c2;
        if (lay == 0) {
            *(float2*)&Y[(b * Tdim + t) * CC + c] = make_float2(v0, v1);
        } else {
            Y[(b * CC + c) * Tdim + t] = v0;
            Y[(b * CC + c + 1) * Tdim + t] = v1;
        }
    }
}

__global__ __launch_bounds__(256) void proj_all(
    const float* __restrict__ q_in, const float* __restrict__ Wq, float* __restrict__ qp,
    const float* __restrict__ k_in, const float* __restrict__ Wk, float* __restrict__ kp,
    const float* __restrict__ v_in, const float* __restrict__ Wv, float* __restrict__ vp)
{
    __shared__ float lds[40 * 68 + 32 * 44];   // max(Q, KV) usage
    const int y = blockIdx.y;
    if (y < 4) {
        if ((int)blockIdx.x >= 64) return;     // KV: 2048/32 = 64 row tiles
        if ((y >> 1) == 0)
            proj_tile<640, 32>(k_in, Wk, kp, SCALE2L2E, 1, TK, blockIdx.x, y & 1, lds);
        else
            proj_tile<640, 32>(v_in, Wv, vp, 1.0f, 0, TK, blockIdx.x, y & 1, lds);
    } else {
        proj_tile<80, 40>(q_in, Wq, qp, SCALE2L2E, 0, TQ, blockIdx.x, y - 4, lds);
    }
}

// ---------------- Kernel 2: scores + softmax ----------------
// Block: 4 waves x 2 q-rows = 8 q-rows. Lane = k within 64-wide k-tile.
// kl[c][64] in LDS (conflict-free); q-row + Wvec via scalar loads (uniform ptrs).
__global__ __launch_bounds__(256) void attn_kernel(const float* __restrict__ qp,
                                                   const float* __restrict__ kp,
                                                   const float* __restrict__ Wvec,
                                                   float* __restrict__ attn_out,
                                                   float* __restrict__ pT) {
    __shared__ float kl[128 * 64];
    __shared__ float pl[8][264];

    const int tid = threadIdx.x;
    const int lane = tid & 63;
    const int w = __builtin_amdgcn_readfirstlane(tid >> 6);
    const int b = blockIdx.y;
    const int q0B = blockIdx.x * 8;
    const int q0 = q0B + w * 2;

    const float* __restrict__ qr0 = qp + (b * TQ + q0) * CC;
    const float* __restrict__ qr1 = qr0 + CC;

    // sum of Wvec (unscaled), all lanes
    float sw = Wvec[lane] + Wvec[64 + lane];
#pragma unroll
    for (int m = 32; m >= 1; m >>= 1) sw += __shfl_xor(sw, m, 64);

    float sc0[4], sc1[4];
    for (int tile = 0; tile < 4; ++tile) {
        const int k0 = tile * 64;
        for (int i = tid; i < 128 * 16; i += 256) {
            int c = i >> 4, j4 = (i & 15) << 2;
            float4 v = *(const float4*)&kp[(b * CC + c) * TK + k0 + j4];
            *(float4*)&kl[c * 64 + j4] = v;
        }
        __syncthreads();

        float a0 = 0.f, a1 = 0.f;
        for (int cc = 0; cc < 128; cc += 32) {
#pragma unroll
            for (int u = 0; u < 32; ++u) {
                const int c = cc + u;
                const float kv = kl[c * 64 + lane];
                const float wc = Wvec[c];        // s_load (uniform)
                const float qa = qr0[c];         // s_load (uniform)
                const float qb = qr1[c];         // s_load (uniform)
                float t0 = fexp2(qa + kv);
                a0 = fmaf(wc, frcp(t0 + 1.f), a0);
                float t1 = fexp2(qb + kv);
                a1 = fmaf(wc, frcp(t1 + 1.f), a1);
            }
        }
        sc0[tile] = sw - 2.f * a0;
        sc1[tile] = sw - 2.f * a1;
        __syncthreads();
    }

    // softmax over 256 (4 regs x 64 lanes) per row
    float m0 = fmaxf(fmaxf(sc0[0], sc0[1]), fmaxf(sc0[2], sc0[3]));
    float m1 = fmaxf(fmaxf(sc1[0], sc1[1]), fmaxf(sc1[2], sc1[3]));
#pragma unroll
    for (int m = 32; m >= 1; m >>= 1) {
        m0 = fmaxf(m0, __shfl_xor(m0, m, 64));
        m1 = fmaxf(m1, __shfl_xor(m1, m, 64));
    }
    float e0[4], e1[4], s0 = 0.f, s1 = 0.f;
#pragma unroll
    for (int t = 0; t < 4; ++t) {
        e0[t] = fexp2((sc0[t] - m0) * L2E); s0 += e0[t];
        e1[t] = fexp2((sc1[t] - m1) * L2E); s1 += e1[t];
    }
#pragma unroll
    for (int m = 32; m >= 1; m >>= 1) {
        s0 += __shfl_xor(s0, m, 64);
        s1 += __shfl_xor(s1, m, 64);
    }
    const float r0 = frcp(s0), r1 = frcp(s1);

#pragma unroll
    for (int t = 0; t < 4; ++t) {
        float p0 = e0[t] * r0, p1 = e1[t] * r1;
        attn_out[(b * TQ + q0)     * TK + t * 64 + lane] = p0;
        attn_out[(b * TQ + q0 + 1) * TK + t * 64 + lane] = p1;
        pl[w * 2 + 0][t * 64 + lane] = p0;
        pl[w * 2 + 1][t * 64 + lane] = p1;
    }
    __syncthreads();

    // cooperative transpose dump: pT[b][k][q0B + j]
    for (int i = tid; i < 2048; i += 256) {
        int k = i >> 3, j = i & 7;
        pT[(b * TK + k) * TQ + q0B + j] = pl[j][k];
    }
}

// ---------------- Kernel 3: PV ----------------
// out[b][c][q] = sum_k p[b][q][k] * v[b][k][c]
// grid (4 q-quarters, 8 c-groups, 8 b) x 256 thr; ch = wave-pair selects 8-c sub-block.
// v rows via wave-uniform s_loads; p via coalesced pT.
__global__ __launch_bounds__(256) void pv_kernel(const float* __restrict__ pT,
                                                 const float* __restrict__ vp,
                                                 float* __restrict__ out) {
    const int tid = threadIdx.x;
    const int qh = blockIdx.x;   // 0..3
    const int cg = blockIdx.y;   // 0..7
    const int b  = blockIdx.z;   // 0..7
    const int ch = __builtin_amdgcn_readfirstlane(tid >> 7);
    const int q = qh * 128 + (tid & 127);
    const int c0 = cg * 16 + ch * 8;

    const float* __restrict__ vb = vp + b * TK * CC + c0;
    const float* __restrict__ pb = pT + b * TK * TQ + q;

    float acc[8];
#pragma unroll
    for (int j = 0; j < 8; ++j) acc[j] = 0.f;

#pragma unroll 8
    for (int k = 0; k < TK; ++k) {
        const float p = pb[k * TQ];
        const float* __restrict__ vr = vb + k * CC;  // uniform -> s_load
#pragma unroll
        for (int j = 0; j < 8; ++j) acc[j] = fmaf(p, vr[j], acc[j]);
    }

#pragma unroll
    for (int j = 0; j < 8; ++j)
        out[(b * CC + c0 + j) * TQ + q] = acc[j];
}

extern "C" void kernel_launch(void* const* d_in, const int* in_sizes, int n_in,
                              void* d_out, int out_size, void* d_ws, size_t ws_size,
                              hipStream_t stream) {
    const float* queries = (const float*)d_in[0];
    const float* keys    = (const float*)d_in[1];
    const float* values  = (const float*)d_in[2];
    const float* Wq      = (const float*)d_in[3];
    const float* Wk      = (const float*)d_in[4];
    const float* Wv      = (const float*)d_in[5];
    const float* Wvec    = (const float*)d_in[6];

    float* out  = (float*)d_out;                 // (8,128,512)
    float* attn = out + BB * CC * TQ;            // (8,512,256)

    float* ws = (float*)d_ws;
    float* qp = ws;                    // [b][t][c] 4096*128, scaled by 2*log2e
    float* kp = qp + 4096 * CC;        // [b][c][t] 2048*128, scaled
    float* vp = kp + 2048 * CC;        // [b][t][c] 2048*128
    float* pT = vp + 2048 * CC;        // [b][k][q] 8*256*512

    // y: 0-1 keys (c-halves), 2-3 values, 4-5 queries
    proj_all<<<dim3(128, 6), 256, 0, stream>>>(
        queries, Wq, qp, keys, Wk, kp, values, Wv, vp);
    attn_kernel<<<dim3(64, 8), 256, 0, stream>>>(qp, kp, Wvec, attn, pT);
    pv_kernel<<<dim3(4, 8, 8), 256, 0, stream>>>(pT, vp, out);
}

// Round 4
// 90.559 us; speedup vs baseline: 2.4821x; 1.1566x over previous
//
#include <hip/hip_runtime.h>

#define TQ 512
#define TK 256
#define BB 8
#define CC 128

// 2*log2(e): projections pre-scaled so exp2(qs+ks) == e^(2(q+k))
#define SCALE2L2E 2.8853900817779268f
#define L2E 1.4426950408889634f

__device__ __forceinline__ float fexp2(float x) { return __builtin_amdgcn_exp2f(x); }
__device__ __forceinline__ float frcp(float x)  { return __builtin_amdgcn_rcpf(x); }

// ---------------- Kernel 1: projection GEMM v4 ----------------
// Y(rows x 128) = X(rows x K) @ W(128 x K)^T ; row r -> (t = r/8, b = r%8).
// Block: 16 rows x 128 cols, 256 threads; thread = 2 rows x 4 cols (acc[2][4]).
// Register-prefetch (T14): chunk kc+1 global loads issued right after LDS
// publish of chunk kc, consumed next iteration -> HBM/L2 latency hides under
// the 512-cy FMA phase. Single LDS buffer, 2 barriers/chunk.
// LDS: ws[KC][132] (W^T chunk; b128 reads 2-way-aliased = free) +
//      xs[16][KC+4] (b128 broadcast reads).
template<int K, int KC>
__global__ __launch_bounds__(256) void proj2(
    const float* __restrict__ X0, const float* __restrict__ W0, float* __restrict__ Y0,
    float sc0, int lay0, int T0,
    const float* __restrict__ X1, const float* __restrict__ W1, float* __restrict__ Y1,
    float sc1, int lay1, int T1)
{
    constexpr int NCH = K / KC;
    constexpr int KC4 = KC / 4;
    constexpr int WROW = 132;
    constexpr int XPAD = KC + 4;
    constexpr int NXJ = 16 * KC4;               // X float4 jobs
    constexpr int NWJ = (128 * KC4) / 256;      // W float4 jobs per thread (exact)

    __shared__ float ws[KC][WROW];
    __shared__ float xs[16][XPAD];

    const int y = blockIdx.y;
    const float* __restrict__ X = y ? X1 : X0;
    const float* __restrict__ W = y ? W1 : W0;
    float* __restrict__ Y = y ? Y1 : Y0;
    const float scale = y ? sc1 : sc0;
    const int lay = y ? lay1 : lay0;
    const int Tdim = y ? T1 : T0;

    const int tid = threadIdx.x;
    const int r0 = blockIdx.x * 16;

    const int xr = tid / KC4, xj = tid % KC4;   // X stage job (if tid < NXJ)

    float4 px;
    float4 pw[NWJ];

    auto issue = [&](int kc) {
        if (tid < NXJ)
            px = *(const float4*)&X[(r0 + xr) * K + kc * KC + xj * 4];
#pragma unroll
        for (int m = 0; m < NWJ; ++m) {
            int i = tid + 256 * m;
            int c = i / KC4, j = i % KC4;
            pw[m] = *(const float4*)&W[c * K + kc * KC + j * 4];
        }
    };

    issue(0);

    const int rg = tid >> 5;          // 0..7 -> rows rg*2, rg*2+1
    const int c4 = (tid & 31) * 4;    // 0,4,...,124

    float acc[2][4];
#pragma unroll
    for (int i = 0; i < 2; ++i)
#pragma unroll
        for (int j = 0; j < 4; ++j) acc[i][j] = 0.f;

    for (int kc = 0; kc < NCH; ++kc) {
        if (kc) __syncthreads();                 // prev-chunk readers done
        // publish prefetched chunk to LDS (implicit vmcnt wait here)
        if (tid < NXJ)
            *(float4*)&xs[xr][xj * 4] = px;
#pragma unroll
        for (int m = 0; m < NWJ; ++m) {
            int i = tid + 256 * m;
            int c = i / KC4, j = i % KC4;
            ws[j * 4 + 0][c] = pw[m].x;
            ws[j * 4 + 1][c] = pw[m].y;
            ws[j * 4 + 2][c] = pw[m].z;
            ws[j * 4 + 3][c] = pw[m].w;
        }
        __syncthreads();
        if (kc + 1 < NCH) issue(kc + 1);         // in flight under compute

#pragma unroll
        for (int k4 = 0; k4 < KC4; ++k4) {
            float4 wv[4];
            float4 xv[2];
#pragma unroll
            for (int m = 0; m < 4; ++m)
                wv[m] = *(const float4*)&ws[k4 * 4 + m][c4];
#pragma unroll
            for (int i = 0; i < 2; ++i)
                xv[i] = *(const float4*)&xs[rg * 2 + i][k4 * 4];
#pragma unroll
            for (int i = 0; i < 2; ++i) {
                const float xa[4] = {xv[i].x, xv[i].y, xv[i].z, xv[i].w};
#pragma unroll
                for (int m = 0; m < 4; ++m) {
                    acc[i][0] = fmaf(xa[m], wv[m].x, acc[i][0]);
                    acc[i][1] = fmaf(xa[m], wv[m].y, acc[i][1]);
                    acc[i][2] = fmaf(xa[m], wv[m].z, acc[i][2]);
                    acc[i][3] = fmaf(xa[m], wv[m].w, acc[i][3]);
                }
            }
        }
    }

#pragma unroll
    for (int i = 0; i < 2; ++i) {
        int grow = r0 + rg * 2 + i;
        int t = grow >> 3, b = grow & 7;
        float v0 = acc[i][0] * scale, v1 = acc[i][1] * scale;
        float v2 = acc[i][2] * scale, v3 = acc[i][3] * scale;
        if (lay == 0) {
            *(float4*)&Y[(b * Tdim + t) * CC + c4] = make_float4(v0, v1, v2, v3);
        } else {
            Y[(b * CC + c4 + 0) * Tdim + t] = v0;
            Y[(b * CC + c4 + 1) * Tdim + t] = v1;
            Y[(b * CC + c4 + 2) * Tdim + t] = v2;
            Y[(b * CC + c4 + 3) * Tdim + t] = v3;
        }
    }
}

// ---------------- Kernel 2: scores + softmax ----------------
// Block: 4 waves x 2 q-rows = 8 q-rows. Lane = k within 64-wide k-tile.
// kl[c][64] in LDS (conflict-free); q-row + Wvec via scalar loads (uniform ptrs).
__global__ __launch_bounds__(256) void attn_kernel(const float* __restrict__ qp,
                                                   const float* __restrict__ kp,
                                                   const float* __restrict__ Wvec,
                                                   float* __restrict__ attn_out,
                                                   float* __restrict__ pT) {
    __shared__ float kl[128 * 64];
    __shared__ float pl[8][264];

    const int tid = threadIdx.x;
    const int lane = tid & 63;
    const int w = __builtin_amdgcn_readfirstlane(tid >> 6);
    const int b = blockIdx.y;
    const int q0B = blockIdx.x * 8;
    const int q0 = q0B + w * 2;

    const float* __restrict__ qr0 = qp + (b * TQ + q0) * CC;
    const float* __restrict__ qr1 = qr0 + CC;

    // sum of Wvec (unscaled), all lanes
    float sw = Wvec[lane] + Wvec[64 + lane];
#pragma unroll
    for (int m = 32; m >= 1; m >>= 1) sw += __shfl_xor(sw, m, 64);

    float sc0[4], sc1[4];
    for (int tile = 0; tile < 4; ++tile) {
        const int k0 = tile * 64;
        for (int i = tid; i < 128 * 16; i += 256) {
            int c = i >> 4, j4 = (i & 15) << 2;
            float4 v = *(const float4*)&kp[(b * CC + c) * TK + k0 + j4];
            *(float4*)&kl[c * 64 + j4] = v;
        }
        __syncthreads();

        float a0 = 0.f, a1 = 0.f;
        for (int cc = 0; cc < 128; cc += 32) {
#pragma unroll
            for (int u = 0; u < 32; ++u) {
                const int c = cc + u;
                const float kv = kl[c * 64 + lane];
                const float wc = Wvec[c];        // s_load (uniform)
                const float qa = qr0[c];         // s_load (uniform)
                const float qb = qr1[c];         // s_load (uniform)
                float t0 = fexp2(qa + kv);
                a0 = fmaf(wc, frcp(t0 + 1.f), a0);
                float t1 = fexp2(qb + kv);
                a1 = fmaf(wc, frcp(t1 + 1.f), a1);
            }
        }
        sc0[tile] = sw - 2.f * a0;
        sc1[tile] = sw - 2.f * a1;
        __syncthreads();
    }

    // softmax over 256 (4 regs x 64 lanes) per row
    float m0 = fmaxf(fmaxf(sc0[0], sc0[1]), fmaxf(sc0[2], sc0[3]));
    float m1 = fmaxf(fmaxf(sc1[0], sc1[1]), fmaxf(sc1[2], sc1[3]));
#pragma unroll
    for (int m = 32; m >= 1; m >>= 1) {
        m0 = fmaxf(m0, __shfl_xor(m0, m, 64));
        m1 = fmaxf(m1, __shfl_xor(m1, m, 64));
    }
    float e0[4], e1[4], s0 = 0.f, s1 = 0.f;
#pragma unroll
    for (int t = 0; t < 4; ++t) {
        e0[t] = fexp2((sc0[t] - m0) * L2E); s0 += e0[t];
        e1[t] = fexp2((sc1[t] - m1) * L2E); s1 += e1[t];
    }
#pragma unroll
    for (int m = 32; m >= 1; m >>= 1) {
        s0 += __shfl_xor(s0, m, 64);
        s1 += __shfl_xor(s1, m, 64);
    }
    const float r0 = frcp(s0), r1 = frcp(s1);

#pragma unroll
    for (int t = 0; t < 4; ++t) {
        float p0 = e0[t] * r0, p1 = e1[t] * r1;
        attn_out[(b * TQ + q0)     * TK + t * 64 + lane] = p0;
        attn_out[(b * TQ + q0 + 1) * TK + t * 64 + lane] = p1;
        pl[w * 2 + 0][t * 64 + lane] = p0;
        pl[w * 2 + 1][t * 64 + lane] = p1;
    }
    __syncthreads();

    // cooperative transpose dump: pT[b][k][q0B + j]
    for (int i = tid; i < 2048; i += 256) {
        int k = i >> 3, j = i & 7;
        pT[(b * TK + k) * TQ + q0B + j] = pl[j][k];
    }
}

// ---------------- Kernel 3: PV ----------------
// out[b][c][q] = sum_k p[b][q][k] * v[b][k][c]
// grid (4 q-quarters, 8 c-groups, 8 b) x 256 thr; ch = wave-pair selects 8-c sub-block.
// v rows via wave-uniform s_loads; p via coalesced pT.
__global__ __launch_bounds__(256) void pv_kernel(const float* __restrict__ pT,
                                                 const float* __restrict__ vp,
                                                 float* __restrict__ out) {
    const int tid = threadIdx.x;
    const int qh = blockIdx.x;   // 0..3
    const int cg = blockIdx.y;   // 0..7
    const int b  = blockIdx.z;   // 0..7
    const int ch = __builtin_amdgcn_readfirstlane(tid >> 7);
    const int q = qh * 128 + (tid & 127);
    const int c0 = cg * 16 + ch * 8;

    const float* __restrict__ vb = vp + b * TK * CC + c0;
    const float* __restrict__ pb = pT + b * TK * TQ + q;

    float acc[8];
#pragma unroll
    for (int j = 0; j < 8; ++j) acc[j] = 0.f;

#pragma unroll 8
    for (int k = 0; k < TK; ++k) {
        const float p = pb[k * TQ];
        const float* __restrict__ vr = vb + k * CC;  // uniform -> s_load
#pragma unroll
        for (int j = 0; j < 8; ++j) acc[j] = fmaf(p, vr[j], acc[j]);
    }

#pragma unroll
    for (int j = 0; j < 8; ++j)
        out[(b * CC + c0 + j) * TQ + q] = acc[j];
}

extern "C" void kernel_launch(void* const* d_in, const int* in_sizes, int n_in,
                              void* d_out, int out_size, void* d_ws, size_t ws_size,
                              hipStream_t stream) {
    const float* queries = (const float*)d_in[0];
    const float* keys    = (const float*)d_in[1];
    const float* values  = (const float*)d_in[2];
    const float* Wq      = (const float*)d_in[3];
    const float* Wk      = (const float*)d_in[4];
    const float* Wv      = (const float*)d_in[5];
    const float* Wvec    = (const float*)d_in[6];

    float* out  = (float*)d_out;                 // (8,128,512)
    float* attn = out + BB * CC * TQ;            // (8,512,256)

    float* ws = (float*)d_ws;
    float* qp = ws;                    // [b][t][c] 4096*128, scaled by 2*log2e
    float* kp = qp + 4096 * CC;        // [b][c][t] 2048*128, scaled
    float* vp = kp + 2048 * CC;        // [b][t][c] 2048*128
    float* pT = vp + 2048 * CC;        // [b][k][q] 8*256*512

    // KV: 128 row-tiles x {keys, values}; 2048 waves
    proj2<640, 32><<<dim3(128, 2), 256, 0, stream>>>(
        keys, Wk, kp, SCALE2L2E, 1, TK,
        values, Wv, vp, 1.0f, 0, TK);
    // Q: 256 row-tiles; 1024 waves
    proj2<80, 40><<<dim3(256, 1), 256, 0, stream>>>(
        queries, Wq, qp, SCALE2L2E, 0, TQ,
        queries, Wq, qp, SCALE2L2E, 0, TQ);
    attn_kernel<<<dim3(64, 8), 256, 0, stream>>>(qp, kp, Wvec, attn, pT);
    pv_kernel<<<dim3(4, 8, 8), 256, 0, stream>>>(pT, vp, out);
}